// Round 1
// baseline (978.525 us; speedup 1.0000x reference)
//
#include <hip/hip_runtime.h>

#define NS 500000
#define NG 20000
#define NN 600000
#define NF 8
#define EPS_ 1e-5f

// ---------------- K1: w = mean_f filters; also copy filters -> out ----------------
__global__ __launch_bounds__(256) void k_w_copy(const float* __restrict__ filters,
                                                float* __restrict__ w,
                                                float* __restrict__ out_f) {
  int i = blockIdx.x * 256 + threadIdx.x;
  const int n4 = NS / 4;  // 125000
  if (i >= n4) return;
  const float4* f4 = (const float4*)filters;
  float4* o4 = (float4*)out_f;
  float sx = 0.f, sy = 0.f, sz = 0.f, sw = 0.f;
#pragma unroll
  for (int f = 0; f < NF; f++) {
    float4 v = f4[(size_t)f * n4 + i];
    o4[(size_t)f * n4 + i] = v;
    sx += v.x; sy += v.y; sz += v.z; sw += v.w;
  }
  float4 r;
  r.x = sx * 0.125f; r.y = sy * 0.125f; r.z = sz * 0.125f; r.w = sw * 0.125f;
  ((float4*)w)[i] = r;
}

// ---------------- K2: transpose snp[64][NS] -> snpT[NS][64] ----------------
__global__ __launch_bounds__(256) void k_transpose(const float* __restrict__ snp,
                                                   float* __restrict__ snpT) {
  __shared__ float tile[64][65];
  int tid = threadIdx.x;
  int s0 = blockIdx.x * 64;
  int c = tid & 63;       // snp column within tile
  int r4 = tid >> 6;      // 0..3
#pragma unroll
  for (int r = 0; r < 64; r += 4) {
    int b = r + r4;
    int s = s0 + c;
    tile[b][c] = (s < NS) ? snp[(size_t)b * NS + s] : 0.f;
  }
  __syncthreads();
#pragma unroll
  for (int r = 0; r < 64; r += 4) {
    int srow = r + r4;
    int s = s0 + srow;
    if (s < NS) snpT[(size_t)s * 64 + c] = tile[c][srow];
  }
}

// ---------------- K3a: histogram of node_gene ----------------
__global__ __launch_bounds__(256) void k_hist(const int* __restrict__ node_gene,
                                              int* __restrict__ cnt) {
  int j = blockIdx.x * 256 + threadIdx.x;
  if (j < NN) atomicAdd(&cnt[node_gene[j]], 1);
}

// ---------------- K3b: exclusive scan over 20000 counters (1 block, 1024 thr) ----------------
__global__ __launch_bounds__(1024) void k_scan(const int* __restrict__ cnt,
                                               int* __restrict__ offs,
                                               int* __restrict__ cursor) {
  __shared__ int part[1024];
  int t = threadIdx.x;
  int base = t * 20;  // 1024*20 = 20480 >= 20000
  int s = 0;
  for (int i = 0; i < 20; i++) {
    int g = base + i;
    if (g < NG) s += cnt[g];
  }
  part[t] = s;
  __syncthreads();
  for (int d = 1; d < 1024; d <<= 1) {
    int v = 0;
    if (t >= d) v = part[t - d];
    __syncthreads();
    part[t] += v;
    __syncthreads();
  }
  int run = part[t] - s;  // exclusive base for this strip
  for (int i = 0; i < 20; i++) {
    int g = base + i;
    if (g < NG) {
      offs[g] = run;
      cursor[g] = run;
      run += cnt[g];
    }
  }
  if (t == 1023) offs[NG] = part[1023];
}

// ---------------- K3c: scatter node sids into gene-sorted order ----------------
__global__ __launch_bounds__(256) void k_sortnodes(const int* __restrict__ snp_ids,
                                                   const int* __restrict__ node_gene,
                                                   int* __restrict__ cursor,
                                                   int* __restrict__ sorted_sid) {
  int j = blockIdx.x * 256 + threadIdx.x;
  if (j >= NN) return;
  int g = node_gene[j];
  int pos = atomicAdd(&cursor[g], 1);
  sorted_sid[pos] = snp_ids[j];
}

// ---------------- K4: per-gene accumulation, wave per gene, lane = batch ----------------
__global__ __launch_bounds__(256) void k_accum_T(const float* __restrict__ snpT,
                                                 const float* __restrict__ w,
                                                 const int* __restrict__ offs,
                                                 const int* __restrict__ sorted_sid,
                                                 float* __restrict__ geneT) {
  int wave = (blockIdx.x * 256 + threadIdx.x) >> 6;
  int lane = threadIdx.x & 63;
  if (wave >= NG) return;
  int beg = offs[wave], end = offs[wave + 1];
  float acc = 0.f;
  int n = beg;
  for (; n + 4 <= end; n += 4) {
    int s0 = sorted_sid[n], s1 = sorted_sid[n + 1];
    int s2 = sorted_sid[n + 2], s3 = sorted_sid[n + 3];
    float a0 = snpT[(size_t)s0 * 64 + lane] * w[s0];
    float a1 = snpT[(size_t)s1 * 64 + lane] * w[s1];
    float a2 = snpT[(size_t)s2 * 64 + lane] * w[s2];
    float a3 = snpT[(size_t)s3 * 64 + lane] * w[s3];
    acc += a0 + a1 + a2 + a3;
  }
  for (; n < end; n++) {
    int s = sorted_sid[n];
    acc += snpT[(size_t)s * 64 + lane] * w[s];
  }
  geneT[(size_t)wave * 64 + lane] = acc;
}

// Fallback when ws too small for snpT: gather directly from snp (uncoalesced)
__global__ __launch_bounds__(256) void k_accum_D(const float* __restrict__ snp,
                                                 const float* __restrict__ w,
                                                 const int* __restrict__ offs,
                                                 const int* __restrict__ sorted_sid,
                                                 float* __restrict__ geneT) {
  int wave = (blockIdx.x * 256 + threadIdx.x) >> 6;
  int lane = threadIdx.x & 63;
  if (wave >= NG) return;
  int beg = offs[wave], end = offs[wave + 1];
  float acc = 0.f;
  for (int n = beg; n < end; n++) {
    int s = sorted_sid[n];
    acc += snp[(size_t)lane * NS + s] * w[s];
  }
  geneT[(size_t)wave * 64 + lane] = acc;
}

// ---------------- GEMM: outT[n][b] += sum_k XT[k][b] * Wm[k][n] ----------------
// block = 256 thr = 4 waves; each wave owns 8 columns; LDS tile 128k x 64b.
template <int NCOLS, int KTOT>
__global__ __launch_bounds__(256) void k_gemm(const float* __restrict__ XT,
                                              const float* __restrict__ Wm,
                                              float* __restrict__ outT,
                                              int tilesPerSlice) {
  __shared__ float tile[128 * 64];
  int tid = threadIdx.x;
  int lane = tid & 63;
  int wid = tid >> 6;
  int n0 = blockIdx.x * 32 + wid * 8;
  int k0 = blockIdx.y * tilesPerSlice * 128;
  float acc0 = 0.f, acc1 = 0.f, acc2 = 0.f, acc3 = 0.f;
  float acc4 = 0.f, acc5 = 0.f, acc6 = 0.f, acc7 = 0.f;
  const float4* src = (const float4*)XT;
  for (int t = 0; t < tilesPerSlice; t++) {
    int kb = k0 + t * 128;
    for (int i = tid; i < 2048; i += 256) {
      int gi = kb * 16 + i;
      float4 v = make_float4(0.f, 0.f, 0.f, 0.f);
      if (gi < KTOT * 16) v = src[gi];
      ((float4*)tile)[i] = v;
    }
    __syncthreads();
#pragma unroll 8
    for (int kk = 0; kk < 128; kk++) {
      int kr = kb + kk;
      int krc = kr < KTOT ? kr : (KTOT - 1);
      const float* wrow = Wm + (size_t)krc * NCOLS + n0;
      float4 wa = *(const float4*)wrow;
      float4 wb = *(const float4*)(wrow + 4);
      float g = tile[kk * 64 + lane];
      acc0 = fmaf(g, wa.x, acc0);
      acc1 = fmaf(g, wa.y, acc1);
      acc2 = fmaf(g, wa.z, acc2);
      acc3 = fmaf(g, wa.w, acc3);
      acc4 = fmaf(g, wb.x, acc4);
      acc5 = fmaf(g, wb.y, acc5);
      acc6 = fmaf(g, wb.z, acc6);
      acc7 = fmaf(g, wb.w, acc7);
    }
    __syncthreads();
  }
  atomicAdd(&outT[(size_t)(n0 + 0) * 64 + lane], acc0);
  atomicAdd(&outT[(size_t)(n0 + 1) * 64 + lane], acc1);
  atomicAdd(&outT[(size_t)(n0 + 2) * 64 + lane], acc2);
  atomicAdd(&outT[(size_t)(n0 + 3) * 64 + lane], acc3);
  atomicAdd(&outT[(size_t)(n0 + 4) * 64 + lane], acc4);
  atomicAdd(&outT[(size_t)(n0 + 5) * 64 + lane], acc5);
  atomicAdd(&outT[(size_t)(n0 + 6) * 64 + lane], acc6);
  atomicAdd(&outT[(size_t)(n0 + 7) * 64 + lane], acc7);
}

// ---------------- BN (+ReLU) over batch axis; one block (1 wave) per column ----------------
__global__ __launch_bounds__(64) void k_bn(const float* __restrict__ preT,
                                           const float* __restrict__ gamma,
                                           const float* __restrict__ beta,
                                           float* __restrict__ outT) {
  int n = blockIdx.x;
  int b = threadIdx.x;
  float x = preT[(size_t)n * 64 + b];
  float s = x, s2 = x * x;
#pragma unroll
  for (int d = 32; d > 0; d >>= 1) {
    s += __shfl_xor(s, d, 64);
    s2 += __shfl_xor(s2, d, 64);
  }
  float m = s * (1.f / 64.f);
  float v = s2 * (1.f / 64.f) - m * m;
  float y = gamma[n] * (x - m) * rsqrtf(v + EPS_) + beta[n];
  outT[(size_t)n * 64 + b] = fmaxf(y, 0.f);
}

// ---------------- head: preds[b] = sum_k h2T[k][b]*W3[k] + b3 ----------------
__global__ __launch_bounds__(64) void k_head(const float* __restrict__ h2T,
                                             const float* __restrict__ W3,
                                             const float* __restrict__ b3,
                                             float* __restrict__ out) {
  int b = threadIdx.x;
  float acc = 0.f;
  for (int k = 0; k < 256; k++) acc = fmaf(h2T[(size_t)k * 64 + b], W3[k], acc);
  out[b] = acc + b3[0];
}

// ---------------- workspace layout (element units, 4 B each) ----------------
// w[500000] | snpT[NS*64] | geneT[NG*64] | h1preT[65536] | h1T[65536] |
// h2preT[16384] | h2T[16384] | ints: cnt[20000] offs[20001..pad 20064] cursor[20000] sorted[600000]
static constexpr size_t N_W = 500000;
static constexpr size_t N_SNPT = (size_t)NS * 64;         // 32,000,000
static constexpr size_t N_GENET = (size_t)NG * 64;        // 1,280,000
static constexpr size_t N_CHAIN = N_GENET + 65536 + 65536 + 16384 + 16384 + 660064;
static constexpr size_t FULL_ELEMS = N_W + N_SNPT + N_CHAIN;
static constexpr size_t SMALL_ELEMS = N_W + N_CHAIN;

extern "C" void kernel_launch(void* const* d_in, const int* in_sizes, int n_in,
                              void* d_out, int out_size, void* d_ws, size_t ws_size,
                              hipStream_t stream) {
  const float* snp       = (const float*)d_in[0];
  const int*   snp_ids   = (const int*)d_in[1];
  const int*   node_gene = (const int*)d_in[2];
  const float* filters   = (const float*)d_in[3];
  const float* W1        = (const float*)d_in[4];
  const float* g1        = (const float*)d_in[6];
  const float* beta1     = (const float*)d_in[7];
  const float* W2        = (const float*)d_in[8];
  const float* g2        = (const float*)d_in[10];
  const float* beta2     = (const float*)d_in[11];
  const float* W3        = (const float*)d_in[12];
  const float* b3        = (const float*)d_in[13];
  float* out = (float*)d_out;
  float* ws  = (float*)d_ws;

  bool full = ws_size >= FULL_ELEMS * sizeof(float);

  float* w     = ws;                       // 500000
  float* snpT  = ws + N_W;                 // only in full mode
  float* geneT = ws + (full ? (N_W + N_SNPT) : N_W);
  float* h1preT = geneT + N_GENET;
  float* h1T    = h1preT + 65536;
  float* h2preT = h1T + 65536;
  float* h2T    = h2preT + 16384;
  int* ibase  = (int*)(h2T + 16384);
  int* cnt    = ibase;
  int* offs   = ibase + 20000;   // 20001 used
  int* cursor = ibase + 40064;
  int* sorted = ibase + 60064;   // 600000

  // K1: w + filters passthrough (out[64..])
  k_w_copy<<<(NS / 4 + 255) / 256, 256, 0, stream>>>(filters, w, out + 64);

  // K2: transpose (full mode only)
  if (full) k_transpose<<<(NS + 63) / 64, 256, 0, stream>>>(snp, snpT);

  // zero pre-activation buffers + histogram counters
  hipMemsetAsync(h1preT, 0, (65536 + 65536 + 16384 + 16384) * sizeof(float), stream);
  hipMemsetAsync(cnt, 0, 20000 * sizeof(int), stream);

  // counting sort of nodes by gene
  k_hist<<<(NN + 255) / 256, 256, 0, stream>>>(node_gene, cnt);
  k_scan<<<1, 1024, 0, stream>>>(cnt, offs, cursor);
  k_sortnodes<<<(NN + 255) / 256, 256, 0, stream>>>(snp_ids, node_gene, cursor, sorted);

  // per-gene accumulation (wave per gene, lane = batch)
  if (full)
    k_accum_T<<<(NG * 64) / 256, 256, 0, stream>>>(snpT, w, offs, sorted, geneT);
  else
    k_accum_D<<<(NG * 64) / 256, 256, 0, stream>>>(snp, w, offs, sorted, geneT);

  // MLP
  k_gemm<1024, NG><<<dim3(32, 16), 256, 0, stream>>>(geneT, W1, h1preT, 10);   // 16*10*128 = 20480 >= 20000
  k_bn<<<1024, 64, 0, stream>>>(h1preT, g1, beta1, h1T);
  k_gemm<256, 1024><<<dim3(8, 8), 256, 0, stream>>>(h1T, W2, h2preT, 1);       // 8*128 = 1024
  k_bn<<<256, 64, 0, stream>>>(h2preT, g2, beta2, h2T);
  k_head<<<1, 64, 0, stream>>>(h2T, W3, b3, out);
}

// Round 2
// 535.482 us; speedup vs baseline: 1.8274x; 1.8274x over previous
//
#include <hip/hip_runtime.h>

#define NS 500000
#define NG 20000
#define NN 600000
#define NF 8
#define EPS_ 1e-5f

// ---------------- K1: w = mean_f filters; also copy filters -> out ----------------
__global__ __launch_bounds__(256) void k_w_copy(const float* __restrict__ filters,
                                                float* __restrict__ w,
                                                float* __restrict__ out_f) {
  int i = blockIdx.x * 256 + threadIdx.x;
  const int n4 = NS / 4;  // 125000
  if (i >= n4) return;
  const float4* f4 = (const float4*)filters;
  float4* o4 = (float4*)out_f;
  float sx = 0.f, sy = 0.f, sz = 0.f, sw = 0.f;
#pragma unroll
  for (int f = 0; f < NF; f++) {
    float4 v = f4[(size_t)f * n4 + i];
    o4[(size_t)f * n4 + i] = v;
    sx += v.x; sy += v.y; sz += v.z; sw += v.w;
  }
  float4 r;
  r.x = sx * 0.125f; r.y = sy * 0.125f; r.z = sz * 0.125f; r.w = sw * 0.125f;
  ((float4*)w)[i] = r;
}

// ---------------- K2: transpose snp[64][NS] -> snpwT[NS][64], fused *w[s] ----------------
__global__ __launch_bounds__(256) void k_transpose(const float* __restrict__ snp,
                                                   const float* __restrict__ w,
                                                   float* __restrict__ snpT) {
  __shared__ float tile[64][65];
  int tid = threadIdx.x;
  int s0 = blockIdx.x * 64;
  int c = tid & 63;       // lane
  int r4 = tid >> 6;      // 0..3
#pragma unroll
  for (int r = 0; r < 64; r += 4) {
    int b = r + r4;
    int s = s0 + c;
    tile[b][c] = (s < NS) ? snp[(size_t)b * NS + s] : 0.f;
  }
  __syncthreads();
#pragma unroll
  for (int r = 0; r < 64; r += 4) {
    int srow = r + r4;
    int s = s0 + srow;
    if (s < NS) snpT[(size_t)s * 64 + c] = tile[c][srow] * w[s];
  }
}

// ---------------- K3a: histogram of node_gene ----------------
__global__ __launch_bounds__(256) void k_hist(const int* __restrict__ node_gene,
                                              int* __restrict__ cnt) {
  int j = blockIdx.x * 256 + threadIdx.x;
  if (j < NN) atomicAdd(&cnt[node_gene[j]], 1);
}

// ---------------- K3b: exclusive scan over 20000 counters (1 block, 1024 thr) ----------------
__global__ __launch_bounds__(1024) void k_scan(const int* __restrict__ cnt,
                                               int* __restrict__ offs,
                                               int* __restrict__ cursor) {
  __shared__ int part[1024];
  int t = threadIdx.x;
  int base = t * 20;  // 1024*20 = 20480 >= 20000
  int s = 0;
  for (int i = 0; i < 20; i++) {
    int g = base + i;
    if (g < NG) s += cnt[g];
  }
  part[t] = s;
  __syncthreads();
  for (int d = 1; d < 1024; d <<= 1) {
    int v = 0;
    if (t >= d) v = part[t - d];
    __syncthreads();
    part[t] += v;
    __syncthreads();
  }
  int run = part[t] - s;  // exclusive base for this strip
  for (int i = 0; i < 20; i++) {
    int g = base + i;
    if (g < NG) {
      offs[g] = run;
      cursor[g] = run;
      run += cnt[g];
    }
  }
  if (t == 1023) offs[NG] = part[1023];
}

// ---------------- K3c: scatter node sids into gene-sorted order ----------------
__global__ __launch_bounds__(256) void k_sortnodes(const int* __restrict__ snp_ids,
                                                   const int* __restrict__ node_gene,
                                                   int* __restrict__ cursor,
                                                   int* __restrict__ sorted_sid) {
  int j = blockIdx.x * 256 + threadIdx.x;
  if (j >= NN) return;
  int g = node_gene[j];
  int pos = atomicAdd(&cursor[g], 1);
  sorted_sid[pos] = snp_ids[j];
}

// ---------------- K4: per-gene accumulation, wave per gene, lane = batch ----------------
// snpT already has w folded in.
__global__ __launch_bounds__(256) void k_accum_T(const float* __restrict__ snpT,
                                                 const int* __restrict__ offs,
                                                 const int* __restrict__ sorted_sid,
                                                 float* __restrict__ geneT) {
  int wave = (blockIdx.x * 256 + threadIdx.x) >> 6;
  int lane = threadIdx.x & 63;
  if (wave >= NG) return;
  int beg = offs[wave], end = offs[wave + 1];
  float acc = 0.f;
  int n = beg;
  for (; n + 4 <= end; n += 4) {
    int s0 = sorted_sid[n], s1 = sorted_sid[n + 1];
    int s2 = sorted_sid[n + 2], s3 = sorted_sid[n + 3];
    float a0 = snpT[(size_t)s0 * 64 + lane];
    float a1 = snpT[(size_t)s1 * 64 + lane];
    float a2 = snpT[(size_t)s2 * 64 + lane];
    float a3 = snpT[(size_t)s3 * 64 + lane];
    acc += (a0 + a1) + (a2 + a3);
  }
  for (; n < end; n++) {
    int s = sorted_sid[n];
    acc += snpT[(size_t)s * 64 + lane];
  }
  geneT[(size_t)wave * 64 + lane] = acc;
}

// Fallback when ws too small for snpT: gather directly from snp (uncoalesced)
__global__ __launch_bounds__(256) void k_accum_D(const float* __restrict__ snp,
                                                 const float* __restrict__ w,
                                                 const int* __restrict__ offs,
                                                 const int* __restrict__ sorted_sid,
                                                 float* __restrict__ geneT) {
  int wave = (blockIdx.x * 256 + threadIdx.x) >> 6;
  int lane = threadIdx.x & 63;
  if (wave >= NG) return;
  int beg = offs[wave], end = offs[wave + 1];
  float acc = 0.f;
  for (int n = beg; n < end; n++) {
    int s = sorted_sid[n];
    acc += snp[(size_t)lane * NS + s] * w[s];
  }
  geneT[(size_t)wave * 64 + lane] = acc;
}

// ---------------- streamed split-K GEMM ----------------
// outT_partial[slice][n][b] += over k-slice of XT[k][b]*Wm[k][n]
// block 256: lane owns 4 consecutive cols (float4 of Wm row), wave owns 16 batches.
// Per k: 1 coalesced float4 W-load + 4 wave-uniform float4 X-loads + 64 FMAs.
template <int NCOLS>
__global__ __launch_bounds__(256) void k_gemm_stream(const float* __restrict__ XT,
                                                     const float* __restrict__ Wm,
                                                     float* __restrict__ partial,
                                                     int KTOT, int kPerSlice) {
  int tid = threadIdx.x;
  int lane = tid & 63;
  int wv = tid >> 6;
  int c0 = blockIdx.x * 256 + lane * 4;
  int b0 = wv * 16;
  int kBeg = blockIdx.y * kPerSlice;
  int kEnd = KTOT < kBeg + kPerSlice ? KTOT : kBeg + kPerSlice;

  float acc[4][16];
#pragma unroll
  for (int i = 0; i < 4; i++)
#pragma unroll
    for (int j = 0; j < 16; j++) acc[i][j] = 0.f;

#pragma unroll 2
  for (int k = kBeg; k < kEnd; k++) {
    float4 wr = *(const float4*)(Wm + (size_t)k * NCOLS + c0);
    const float4* gp = (const float4*)(XT + (size_t)k * 64 + b0);
    float4 g0 = gp[0], g1 = gp[1], g2 = gp[2], g3 = gp[3];
    float gg[16];
    gg[0] = g0.x; gg[1] = g0.y; gg[2] = g0.z; gg[3] = g0.w;
    gg[4] = g1.x; gg[5] = g1.y; gg[6] = g1.z; gg[7] = g1.w;
    gg[8] = g2.x; gg[9] = g2.y; gg[10] = g2.z; gg[11] = g2.w;
    gg[12] = g3.x; gg[13] = g3.y; gg[14] = g3.z; gg[15] = g3.w;
#pragma unroll
    for (int j = 0; j < 16; j++) {
      acc[0][j] = fmaf(wr.x, gg[j], acc[0][j]);
      acc[1][j] = fmaf(wr.y, gg[j], acc[1][j]);
      acc[2][j] = fmaf(wr.z, gg[j], acc[2][j]);
      acc[3][j] = fmaf(wr.w, gg[j], acc[3][j]);
    }
  }

  float* pb = partial + (size_t)blockIdx.y * NCOLS * 64;
#pragma unroll
  for (int i = 0; i < 4; i++) {
    float4* dst = (float4*)(pb + (size_t)(c0 + i) * 64 + b0);
#pragma unroll
    for (int q = 0; q < 4; q++) {
      float4 v;
      v.x = acc[i][q * 4 + 0]; v.y = acc[i][q * 4 + 1];
      v.z = acc[i][q * 4 + 2]; v.w = acc[i][q * 4 + 3];
      dst[q] = v;
    }
  }
}

// ---------------- fused split-K reduce + BatchNorm + ReLU ----------------
// one wave per column n (lane = batch b); 4 columns per block.
__global__ __launch_bounds__(256) void k_reduce_bn(const float* __restrict__ partial,
                                                   int S, int ncols,
                                                   const float* __restrict__ gamma,
                                                   const float* __restrict__ beta,
                                                   float* __restrict__ outT) {
  int n = blockIdx.x * 4 + (threadIdx.x >> 6);
  int b = threadIdx.x & 63;
  size_t stride = (size_t)ncols * 64;
  const float* p = partial + (size_t)n * 64 + b;
  float x0 = 0.f, x1 = 0.f, x2 = 0.f, x3 = 0.f;
  int s = 0;
  for (; s + 4 <= S; s += 4) {
    x0 += p[(size_t)(s + 0) * stride];
    x1 += p[(size_t)(s + 1) * stride];
    x2 += p[(size_t)(s + 2) * stride];
    x3 += p[(size_t)(s + 3) * stride];
  }
  for (; s < S; s++) x0 += p[(size_t)s * stride];
  float x = (x0 + x1) + (x2 + x3);
  float s1 = x, s2 = x * x;
#pragma unroll
  for (int d = 32; d > 0; d >>= 1) {
    s1 += __shfl_xor(s1, d, 64);
    s2 += __shfl_xor(s2, d, 64);
  }
  float m = s1 * (1.f / 64.f);
  float v = s2 * (1.f / 64.f) - m * m;
  float y = gamma[n] * (x - m) * rsqrtf(v + EPS_) + beta[n];
  outT[(size_t)n * 64 + b] = fmaxf(y, 0.f);
}

// ---------------- head: preds[b] = sum_k h2T[k][b]*W3[k] + b3 ----------------
__global__ __launch_bounds__(64) void k_head(const float* __restrict__ h2T,
                                             const float* __restrict__ W3,
                                             const float* __restrict__ b3,
                                             float* __restrict__ out) {
  int b = threadIdx.x;
  float acc = 0.f;
  for (int k = 0; k < 256; k++) acc = fmaf(h2T[(size_t)k * 64 + b], W3[k], acc);
  out[b] = acc + b3[0];
}

// ---------------- workspace layout (fp32 elements) ----------------
static constexpr size_t N_W = 500000;
static constexpr size_t N_SNPT = (size_t)NS * 64;          // 32,000,000
static constexpr size_t N_GENET = (size_t)NG * 64;         // 1,280,000
static constexpr int S1 = 128;                             // split-K slices, GEMM1
static constexpr int S2 = 128;                             // split-K slices, GEMM2
static constexpr size_t N_P1 = (size_t)S1 * 1024 * 64;     // 8,388,608
static constexpr size_t N_P2 = (size_t)S2 * 256 * 64;      // 2,097,152
static constexpr size_t N_INTS = 20000 + 20064 + 20000 + 600000;  // 660,064
// full: w | snpT (aliased by p1,p2 after accum) | geneT | h1T | h2T | ints
static constexpr size_t FULL_ELEMS = N_W + N_SNPT + N_GENET + 65536 + 16384 + N_INTS;
// small: w | p1 | p2 | geneT | h1T | h2T | ints
static constexpr size_t SMALL_ELEMS = N_W + N_P1 + N_P2 + N_GENET + 65536 + 16384 + N_INTS;

extern "C" void kernel_launch(void* const* d_in, const int* in_sizes, int n_in,
                              void* d_out, int out_size, void* d_ws, size_t ws_size,
                              hipStream_t stream) {
  const float* snp       = (const float*)d_in[0];
  const int*   snp_ids   = (const int*)d_in[1];
  const int*   node_gene = (const int*)d_in[2];
  const float* filters   = (const float*)d_in[3];
  const float* W1        = (const float*)d_in[4];
  const float* g1        = (const float*)d_in[6];
  const float* beta1     = (const float*)d_in[7];
  const float* W2        = (const float*)d_in[8];
  const float* g2        = (const float*)d_in[10];
  const float* beta2     = (const float*)d_in[11];
  const float* W3        = (const float*)d_in[12];
  const float* b3        = (const float*)d_in[13];
  float* out = (float*)d_out;
  float* ws  = (float*)d_ws;

  bool full = ws_size >= FULL_ELEMS * sizeof(float);

  float *w, *snpT, *p1, *p2, *geneT, *h1T, *h2T;
  int* ibase;
  if (full) {
    w = ws;
    snpT = ws + N_W;
    p1 = snpT;            // alias: snpT dead after k_accum_T
    p2 = p1 + N_P1;
    geneT = snpT + N_SNPT;
    h1T = geneT + N_GENET;
    h2T = h1T + 65536;
    ibase = (int*)(h2T + 16384);
  } else {
    w = ws;
    p1 = ws + N_W;
    p2 = p1 + N_P1;
    geneT = p2 + N_P2;
    h1T = geneT + N_GENET;
    h2T = h1T + 65536;
    ibase = (int*)(h2T + 16384);
  }
  int* cnt    = ibase;
  int* offs   = ibase + 20000;   // 20001 used, padded to 20064
  int* cursor = ibase + 40064;
  int* sorted = ibase + 60064;   // 600000

  // K1: w + filters passthrough (out[64..])
  k_w_copy<<<(NS / 4 + 255) / 256, 256, 0, stream>>>(filters, w, out + 64);

  // counting sort of nodes by gene
  hipMemsetAsync(cnt, 0, 20000 * sizeof(int), stream);
  k_hist<<<(NN + 255) / 256, 256, 0, stream>>>(node_gene, cnt);
  k_scan<<<1, 1024, 0, stream>>>(cnt, offs, cursor);
  k_sortnodes<<<(NN + 255) / 256, 256, 0, stream>>>(snp_ids, node_gene, cursor, sorted);

  // gather/segment-sum -> geneT[g][b]
  if (full) {
    k_transpose<<<(NS + 63) / 64, 256, 0, stream>>>(snp, w, snpT);
    k_accum_T<<<(NG * 64) / 256, 256, 0, stream>>>(snpT, offs, sorted, geneT);
  } else {
    k_accum_D<<<(NG * 64) / 256, 256, 0, stream>>>(snp, w, offs, sorted, geneT);
  }

  // MLP layer 1: [64,20000]x[20000,1024]
  int kps1 = (NG + S1 - 1) / S1;  // 157
  k_gemm_stream<1024><<<dim3(4, S1), 256, 0, stream>>>(geneT, W1, p1, NG, kps1);
  k_reduce_bn<<<1024 / 4, 256, 0, stream>>>(p1, S1, 1024, g1, beta1, h1T);

  // MLP layer 2: [64,1024]x[1024,256]
  int kps2 = 1024 / S2;  // 8
  k_gemm_stream<256><<<dim3(1, S2), 256, 0, stream>>>(h1T, W2, p2, 1024, kps2);
  k_reduce_bn<<<256 / 4, 256, 0, stream>>>(p2, S2, 256, g2, beta2, h2T);

  // head
  k_head<<<1, 64, 0, stream>>>(h2T, W3, b3, out);
}